// Round 3
// baseline (195.587 us; speedup 1.0000x reference)
//
#include <hip/hip_runtime.h>
#include <math.h>

// Burgers PINN: u = MLP(x,t) (2->10x7->1, tanh), outputs u, f, u_x, u_xx at 1M
// collocation points + plain forward at 3x16384 IC/boundary points.
// Forward-mode AD with 4 channels: (val, d/dx, d/dt, d2/dx2).
//
// R13: FOUR points per thread @ waves_per_eu(1,1). Busy-cycle ledger
// (R10-R12): VALU stream constant ~153k cyc/SIMD (= static count with
// pk_fma=4cyc, trans~8cyc, trans IS counted in VALUBusy) -> the 22% is TRUE
// issue idle (~5k cyc/wave), invariant to occupancy (R5-R9) and not fixed
// by LDS (R11) or rolling (R12). Surviving theory: per-layer weight s_load
// chains stall lockstep co-resident waves; A/B interleave is already
// finest-grain, so the fix is AMORTIZATION: 4 pts/thread makes each weight
// s_load feed 16 pk_fmas (was 8), halving idle fraction per layer.
// VGPR: ~160 state + ~160 preact -> needs the 512-reg budget of 1 wave/EU
// (no spill through 450, m08). Colloc waves: 4096 = 4 rounds over 1024
// SIMDs. Unrolled, kernarg weight pointers (R10 structure; R12's packer
// and marching pointer added VALU work -> dropped).

#define NU_CONST 0.0031830988618379067f   // 0.01 / pi
#define TWO_OVER_LN2 2.8853900817779268f  // 2 / ln(2)
#define NPT 4

typedef float v2f __attribute__((ext_vector_type(2)));

__device__ __forceinline__ v2f splat2(float s) {
    v2f r; r.x = s; r.y = s; return r;
}
__device__ __forceinline__ v2f pk_fma(v2f a, v2f b, v2f c) {
    return __builtin_elementwise_fma(a, b, c);
}

__device__ __forceinline__ float fast_tanh(float x) {
    float e = __builtin_amdgcn_exp2f(x * TWO_OVER_LN2);
    float r = __builtin_amdgcn_rcpf(e + 1.0f);
    return fmaf(-2.0f, r, 1.0f);
}

// Packed tanh on a pair.
__device__ __forceinline__ v2f tanh2(v2f z2) {
    v2f a2 = z2 * splat2(TWO_OVER_LN2);
    v2f e2;
    e2.x = __builtin_amdgcn_exp2f(a2.x);
    e2.y = __builtin_amdgcn_exp2f(a2.y);
    v2f ep = e2 + splat2(1.0f);
    v2f r2;
    r2.x = __builtin_amdgcn_rcpf(ep.x);
    r2.y = __builtin_amdgcn_rcpf(ep.y);
    return pk_fma(splat2(-2.0f), r2, splat2(1.0f));
}

// One hidden 10->10 tanh layer, 4 AD channels, FOUR points per thread.
// W/B are wave-uniform kernarg pointers -> s_load with immediate offsets.
// Each weight pair feeds 16 pk_fmas.
__device__ __forceinline__ void hidden10_ad_x4(const float* __restrict__ W,
                                               const float* __restrict__ B,
                                               float h[NPT][10], float hx[NPT][10],
                                               float ht[NPT][10], float hxx[NPT][10]) {
    v2f Z[NPT][5], Zx[NPT][5], Zt[NPT][5], Zxx[NPT][5];
#pragma unroll
    for (int jp = 0; jp < 5; ++jp) {
        v2f w2 = *(const v2f*)(W + 2 * jp);   // row 0
        v2f b2 = *(const v2f*)(B + 2 * jp);
#pragma unroll
        for (int p = 0; p < NPT; ++p) {
            Z[p][jp]   = pk_fma(splat2(h[p][0]), w2, b2);
            Zx[p][jp]  = splat2(hx[p][0]) * w2;
            Zt[p][jp]  = splat2(ht[p][0]) * w2;
            Zxx[p][jp] = splat2(hxx[p][0]) * w2;
        }
    }
#pragma unroll
    for (int i = 1; i < 10; ++i) {
#pragma unroll
        for (int jp = 0; jp < 5; ++jp) {
            v2f w2 = *(const v2f*)(W + i * 10 + 2 * jp);
#pragma unroll
            for (int p = 0; p < NPT; ++p) {
                Z[p][jp]   = pk_fma(splat2(h[p][i]),   w2, Z[p][jp]);
                Zx[p][jp]  = pk_fma(splat2(hx[p][i]),  w2, Zx[p][jp]);
                Zt[p][jp]  = pk_fma(splat2(ht[p][i]),  w2, Zt[p][jp]);
                Zxx[p][jp] = pk_fma(splat2(hxx[p][i]), w2, Zxx[p][jp]);
            }
        }
    }
#pragma unroll
    for (int p = 0; p < NPT; ++p) {
#pragma unroll
        for (int jp = 0; jp < 5; ++jp) {
            v2f v2v = tanh2(Z[p][jp]);
            v2f s2  = pk_fma(-v2v, v2v, splat2(1.0f));   // 1 - v^2
            v2f sx2 = s2 * Zx[p][jp];
            v2f m2v = splat2(-2.0f) * v2v;
            v2f htn2 = s2 * Zt[p][jp];
            // d2/dx2 tanh(z) = s*zxx + (-2v)*(sx*zx)
            v2f hxxn2 = pk_fma(s2, Zxx[p][jp], m2v * (sx2 * Zx[p][jp]));
            h[p][2*jp]   = v2v.x;   h[p][2*jp+1]   = v2v.y;
            hx[p][2*jp]  = sx2.x;   hx[p][2*jp+1]  = sx2.y;
            ht[p][2*jp]  = htn2.x;  ht[p][2*jp+1]  = htn2.y;
            hxx[p][2*jp] = hxxn2.x; hxx[p][2*jp+1] = hxxn2.y;
        }
    }
}

// Values-only hidden layer (boundary/IC points), packed over j-pairs.
__device__ __forceinline__ void hidden10_fwd(const float* __restrict__ W,
                                             const float* __restrict__ B,
                                             float h[10]) {
    v2f Z[5];
    {
        v2f hs = splat2(h[0]);
#pragma unroll
        for (int jp = 0; jp < 5; ++jp) {
            v2f w2 = *(const v2f*)(W + 2 * jp);
            v2f b2 = *(const v2f*)(B + 2 * jp);
            Z[jp] = pk_fma(hs, w2, b2);
        }
    }
#pragma unroll
    for (int i = 1; i < 10; ++i) {
        v2f hs = splat2(h[i]);
#pragma unroll
        for (int jp = 0; jp < 5; ++jp) {
            v2f w2 = *(const v2f*)(W + i * 10 + 2 * jp);
            Z[jp] = pk_fma(hs, w2, Z[jp]);
        }
    }
#pragma unroll
    for (int jp = 0; jp < 5; ++jp) {
        v2f v2v = tanh2(Z[jp]);
        h[2*jp] = v2v.x;
        h[2*jp+1] = v2v.y;
    }
}

__global__ __launch_bounds__(256)
__attribute__((amdgpu_waves_per_eu(1, 1)))
void pinn_fused_kernel(
    const float* __restrict__ Xf,
    const float* __restrict__ X0, const float* __restrict__ XL,
    const float* __restrict__ XR,
    const float* __restrict__ W1, const float* __restrict__ b1,
    const float* __restrict__ W2, const float* __restrict__ b2,
    const float* __restrict__ W3, const float* __restrict__ b3,
    const float* __restrict__ W4, const float* __restrict__ b4,
    const float* __restrict__ W5, const float* __restrict__ b5,
    const float* __restrict__ W6, const float* __restrict__ b6,
    const float* __restrict__ W7, const float* __restrict__ b7,
    const float* __restrict__ W8, const float* __restrict__ b8,
    const float* __restrict__ W9, const float* __restrict__ b9,
    float* __restrict__ out_u, float* __restrict__ out_f,
    float* __restrict__ out_ux, float* __restrict__ out_uxx,
    float* __restrict__ O0, float* __restrict__ OL, float* __restrict__ OR_,
    int n_colloc_blocks, int NF4, int N0) {
    if ((int)blockIdx.x < n_colloc_blocks) {
        // ------------- collocation path: 4 points, 4 AD channels -------------
        int gid = blockIdx.x * blockDim.x + threadIdx.x;   // quad index
        if (gid >= NF4) return;
        // Points 4*gid .. 4*gid+3: two float4 loads.
        float4 xt01 = ((const float4*)Xf)[2 * gid];
        float4 xt23 = ((const float4*)Xf)[2 * gid + 1];
        float xin[NPT], tin[NPT];
        xin[0] = xt01.x; tin[0] = xt01.y;
        xin[1] = xt01.z; tin[1] = xt01.w;
        xin[2] = xt23.x; tin[2] = xt23.y;
        xin[3] = xt23.z; tin[3] = xt23.w;

        float h[NPT][10], hx[NPT][10], ht[NPT][10], hxx[NPT][10];
        // Layer 1: 2 -> 10, tanh. Seeds: dx=(1,0), dt=(0,1), dxx=0.
#pragma unroll
        for (int jp = 0; jp < 5; ++jp) {
            v2f wx2 = *(const v2f*)(W1 + 2 * jp);        // W1 row 0
            v2f wt2 = *(const v2f*)(W1 + 10 + 2 * jp);   // W1 row 1
            v2f b2  = *(const v2f*)(b1 + 2 * jp);
#pragma unroll
            for (int p = 0; p < NPT; ++p) {
                v2f z2  = pk_fma(splat2(xin[p]), wx2,
                                 pk_fma(splat2(tin[p]), wt2, b2));
                v2f v2v = tanh2(z2);
                v2f s2  = pk_fma(-v2v, v2v, splat2(1.0f));
                v2f sx2 = s2 * wx2;
                v2f m2v = splat2(-2.0f) * v2v;
                v2f st2 = s2 * wt2;
                v2f sxx2 = m2v * (sx2 * wx2);   // zxx = 0 at layer 1
                h[p][2*jp]   = v2v.x;  h[p][2*jp+1]   = v2v.y;
                hx[p][2*jp]  = sx2.x;  hx[p][2*jp+1]  = sx2.y;
                ht[p][2*jp]  = st2.x;  ht[p][2*jp+1]  = st2.y;
                hxx[p][2*jp] = sxx2.x; hxx[p][2*jp+1] = sxx2.y;
            }
        }

        hidden10_ad_x4(W2, b2, h, hx, ht, hxx);
        hidden10_ad_x4(W3, b3, h, hx, ht, hxx);
        hidden10_ad_x4(W4, b4, h, hx, ht, hxx);
        hidden10_ad_x4(W5, b5, h, hx, ht, hxx);
        hidden10_ad_x4(W6, b6, h, hx, ht, hxx);
        hidden10_ad_x4(W7, b7, h, hx, ht, hxx);
        hidden10_ad_x4(W8, b8, h, hx, ht, hxx);

        // Layer 9: 10 -> 1, linear. Packed pairwise dot + horizontal add.
        float u[NPT], ux[NPT], ut[NPT], uxx[NPT];
#pragma unroll
        for (int p = 0; p < NPT; ++p) {
            v2f w0 = *(const v2f*)(W9);
            v2f hu, hxu, htu, hxxu;
            hu.x   = h[p][0];   hu.y   = h[p][1];
            hxu.x  = hx[p][0];  hxu.y  = hx[p][1];
            htu.x  = ht[p][0];  htu.y  = ht[p][1];
            hxxu.x = hxx[p][0]; hxxu.y = hxx[p][1];
            v2f su   = hu   * w0;
            v2f sux  = hxu  * w0;
            v2f sut  = htu  * w0;
            v2f suxx = hxxu * w0;
#pragma unroll
            for (int jp = 1; jp < 5; ++jp) {
                v2f w2 = *(const v2f*)(W9 + 2 * jp);
                v2f a, b, c, d;
                a.x = h[p][2*jp];   a.y = h[p][2*jp+1];
                b.x = hx[p][2*jp];  b.y = hx[p][2*jp+1];
                c.x = ht[p][2*jp];  c.y = ht[p][2*jp+1];
                d.x = hxx[p][2*jp]; d.y = hxx[p][2*jp+1];
                su   = pk_fma(a, w2, su);
                sux  = pk_fma(b, w2, sux);
                sut  = pk_fma(c, w2, sut);
                suxx = pk_fma(d, w2, suxx);
            }
            u[p]   = b9[0] + (su.x + su.y);
            ux[p]  = sux.x + sux.y;
            ut[p]  = sut.x + sut.y;
            uxx[p] = suxx.x + suxx.y;
        }

        float4 st;
        st.x = u[0]; st.y = u[1]; st.z = u[2]; st.w = u[3];
        ((float4*)out_u)[gid] = st;
        st.x = ux[0]; st.y = ux[1]; st.z = ux[2]; st.w = ux[3];
        ((float4*)out_ux)[gid] = st;
        st.x = uxx[0]; st.y = uxx[1]; st.z = uxx[2]; st.w = uxx[3];
        ((float4*)out_uxx)[gid] = st;
        st.x = fmaf(u[0], ux[0], ut[0]) - NU_CONST * uxx[0];
        st.y = fmaf(u[1], ux[1], ut[1]) - NU_CONST * uxx[1];
        st.z = fmaf(u[2], ux[2], ut[2]) - NU_CONST * uxx[2];
        st.w = fmaf(u[3], ux[3], ut[3]) - NU_CONST * uxx[3];
        ((float4*)out_f)[gid] = st;   // u_t + u*u_x - nu*u_xx
    } else {
        // ---------------- forward-only path: IC + boundaries ----------------
        int idx = (blockIdx.x - n_colloc_blocks) * blockDim.x + threadIdx.x;
        if (idx >= 3 * N0) return;
        const float* X;
        float* O;
        int k;
        if (idx < N0)            { X = X0; O = O0;  k = idx; }
        else if (idx < 2 * N0)   { X = XL; O = OL;  k = idx - N0; }
        else                     { X = XR; O = OR_; k = idx - 2 * N0; }

        float2 xt = ((const float2*)X)[k];
        float x = xt.x;
        float t = xt.y;

        float h[10];
#pragma unroll
        for (int j = 0; j < 10; ++j) {
            float z = fmaf(x, W1[j], fmaf(t, W1[10 + j], b1[j]));
            h[j] = fast_tanh(z);
        }
        hidden10_fwd(W2, b2, h);
        hidden10_fwd(W3, b3, h);
        hidden10_fwd(W4, b4, h);
        hidden10_fwd(W5, b5, h);
        hidden10_fwd(W6, b6, h);
        hidden10_fwd(W7, b7, h);
        hidden10_fwd(W8, b8, h);

        float u = b9[0];
#pragma unroll
        for (int i = 0; i < 10; ++i) u = fmaf(h[i], W9[i], u);
        O[k] = u;
    }
}

extern "C" void kernel_launch(void* const* d_in, const int* in_sizes, int n_in,
                              void* d_out, int out_size, void* d_ws, size_t ws_size,
                              hipStream_t stream) {
    const float* Xf = (const float*)d_in[0];
    const float* X0 = (const float*)d_in[1];
    const float* XL = (const float*)d_in[2];
    const float* XR = (const float*)d_in[3];
    const float* W[9];
    const float* B[9];
    for (int i = 0; i < 9; ++i) {
        W[i] = (const float*)d_in[4 + 2 * i];
        B[i] = (const float*)d_in[5 + 2 * i];
    }
    int NF = in_sizes[0] / 2;
    int N0 = in_sizes[1] / 2;
    int NB = in_sizes[2] / 2;
    int NF4 = NF / 4;   // quads of points (NF = 1048576, divisible)

    float* out = (float*)d_out;
    float* out_u   = out;                         // u_pred_f      [NF]
    float* out_0   = out + NF;                    // u_pred_0      [N0]
    float* out_bl  = out + NF + N0;               // u_pred_b_left [NB]
    float* out_br  = out + NF + N0 + NB;          // u_pred_b_right[NB]
    float* out_f   = out + NF + N0 + 2 * NB;      // f             [NF]
    float* out_ux  = out_f + NF;                  // u_x           [NF]
    float* out_uxx = out_ux + NF;                 // u_xx          [NF]

    int n_colloc_blocks = (NF4 + 255) / 256;
    int n_fwd_blocks    = (3 * N0 + 255) / 256;
    dim3 blk(256);
    dim3 grd(n_colloc_blocks + n_fwd_blocks);
    pinn_fused_kernel<<<grd, blk, 0, stream>>>(
        Xf, X0, XL, XR,
        W[0], B[0], W[1], B[1], W[2], B[2], W[3], B[3], W[4], B[4],
        W[5], B[5], W[6], B[6], W[7], B[7], W[8], B[8],
        out_u, out_f, out_ux, out_uxx,
        out_0, out_bl, out_br,
        n_colloc_blocks, NF4, N0);
}

// Round 4
// 183.556 us; speedup vs baseline: 1.0655x; 1.0655x over previous
//
#include <hip/hip_runtime.h>
#include <math.h>

// Burgers PINN: u = MLP(x,t) (2->10x7->1, tanh), outputs u, f, u_x, u_xx at 1M
// collocation points + plain forward at 3x16384 IC/boundary points.
// Forward-mode AD with 4 channels: (val, d/dx, d/dt, d2/dx2).
//
// R14: R10 structure (2 pts/thread, waves_per_eu(2,2), unrolled, kernarg
// weights) + LAUNDERED weight pointers -> VMEM path. Ledger across R10-R13:
// per-wave stall is ~25k cyc INVARIANT to NPT and occupancy -> matches the
// s_load schedule: ISA caps SGPRs at ~102, a layer needs 110 weight floats,
// so s_loads issue in ~8-10 SGPR-window batches x 8 layers x ~300cyc K$
// latency ~ 24k. Fix: launder weight pointers through an opaque VGPR zero
// (asm "+v") so the compiler can't prove uniformity -> global_load_dwordx2
// into VGPRs (256-reg window, deep hoisting, partial vmcnt(N) waits,
// broadcast-coalesced, L1-resident). Same instruction count per weight.
// Falsified en route: SMEM-drain-fixed-by-LDS (R11: per-use ds_read worse),
// I-fetch (R12), occupancy/amortization alone (R5-R9, R13).

#define NU_CONST 0.0031830988618379067f   // 0.01 / pi
#define TWO_OVER_LN2 2.8853900817779268f  // 2 / ln(2)

typedef float v2f __attribute__((ext_vector_type(2)));

__device__ __forceinline__ v2f splat2(float s) {
    v2f r; r.x = s; r.y = s; return r;
}
__device__ __forceinline__ v2f pk_fma(v2f a, v2f b, v2f c) {
    return __builtin_elementwise_fma(a, b, c);
}

__device__ __forceinline__ float fast_tanh(float x) {
    float e = __builtin_amdgcn_exp2f(x * TWO_OVER_LN2);
    float r = __builtin_amdgcn_rcpf(e + 1.0f);
    return fmaf(-2.0f, r, 1.0f);
}

// Packed tanh on a pair.
__device__ __forceinline__ v2f tanh2(v2f z2) {
    v2f a2 = z2 * splat2(TWO_OVER_LN2);
    v2f e2;
    e2.x = __builtin_amdgcn_exp2f(a2.x);
    e2.y = __builtin_amdgcn_exp2f(a2.y);
    v2f ep = e2 + splat2(1.0f);
    v2f r2;
    r2.x = __builtin_amdgcn_rcpf(ep.x);
    r2.y = __builtin_amdgcn_rcpf(ep.y);
    return pk_fma(splat2(-2.0f), r2, splat2(1.0f));
}

// One hidden 10->10 tanh layer, 4 AD channels, TWO points per thread.
// W/B are laundered (VGPR-offset) pointers -> global_load into VGPRs.
// Each weight pair feeds 8 pk_fmas.
__device__ __forceinline__ void hidden10_ad_x2(const float* __restrict__ W,
                                               const float* __restrict__ B,
                                               float h[2][10], float hx[2][10],
                                               float ht[2][10], float hxx[2][10]) {
    v2f Z[2][5], Zx[2][5], Zt[2][5], Zxx[2][5];
#pragma unroll
    for (int jp = 0; jp < 5; ++jp) {
        v2f w2 = *(const v2f*)(W + 2 * jp);   // row 0
        v2f b2 = *(const v2f*)(B + 2 * jp);
#pragma unroll
        for (int p = 0; p < 2; ++p) {
            Z[p][jp]   = pk_fma(splat2(h[p][0]), w2, b2);
            Zx[p][jp]  = splat2(hx[p][0]) * w2;
            Zt[p][jp]  = splat2(ht[p][0]) * w2;
            Zxx[p][jp] = splat2(hxx[p][0]) * w2;
        }
    }
#pragma unroll
    for (int i = 1; i < 10; ++i) {
#pragma unroll
        for (int jp = 0; jp < 5; ++jp) {
            v2f w2 = *(const v2f*)(W + i * 10 + 2 * jp);
#pragma unroll
            for (int p = 0; p < 2; ++p) {
                Z[p][jp]   = pk_fma(splat2(h[p][i]),   w2, Z[p][jp]);
                Zx[p][jp]  = pk_fma(splat2(hx[p][i]),  w2, Zx[p][jp]);
                Zt[p][jp]  = pk_fma(splat2(ht[p][i]),  w2, Zt[p][jp]);
                Zxx[p][jp] = pk_fma(splat2(hxx[p][i]), w2, Zxx[p][jp]);
            }
        }
    }
#pragma unroll
    for (int p = 0; p < 2; ++p) {
#pragma unroll
        for (int jp = 0; jp < 5; ++jp) {
            v2f v2v = tanh2(Z[p][jp]);
            v2f s2  = pk_fma(-v2v, v2v, splat2(1.0f));   // 1 - v^2
            v2f sx2 = s2 * Zx[p][jp];
            v2f m2v = splat2(-2.0f) * v2v;
            v2f htn2 = s2 * Zt[p][jp];
            // d2/dx2 tanh(z) = s*zxx + (-2v)*(sx*zx)
            v2f hxxn2 = pk_fma(s2, Zxx[p][jp], m2v * (sx2 * Zx[p][jp]));
            h[p][2*jp]   = v2v.x;   h[p][2*jp+1]   = v2v.y;
            hx[p][2*jp]  = sx2.x;   hx[p][2*jp+1]  = sx2.y;
            ht[p][2*jp]  = htn2.x;  ht[p][2*jp+1]  = htn2.y;
            hxx[p][2*jp] = hxxn2.x; hxx[p][2*jp+1] = hxxn2.y;
        }
    }
}

// Values-only hidden layer (boundary/IC points), packed over j-pairs.
__device__ __forceinline__ void hidden10_fwd(const float* __restrict__ W,
                                             const float* __restrict__ B,
                                             float h[10]) {
    v2f Z[5];
    {
        v2f hs = splat2(h[0]);
#pragma unroll
        for (int jp = 0; jp < 5; ++jp) {
            v2f w2 = *(const v2f*)(W + 2 * jp);
            v2f b2 = *(const v2f*)(B + 2 * jp);
            Z[jp] = pk_fma(hs, w2, b2);
        }
    }
#pragma unroll
    for (int i = 1; i < 10; ++i) {
        v2f hs = splat2(h[i]);
#pragma unroll
        for (int jp = 0; jp < 5; ++jp) {
            v2f w2 = *(const v2f*)(W + i * 10 + 2 * jp);
            Z[jp] = pk_fma(hs, w2, Z[jp]);
        }
    }
#pragma unroll
    for (int jp = 0; jp < 5; ++jp) {
        v2f v2v = tanh2(Z[jp]);
        h[2*jp] = v2v.x;
        h[2*jp+1] = v2v.y;
    }
}

__global__ __launch_bounds__(256)
__attribute__((amdgpu_waves_per_eu(2, 2)))
void pinn_fused_kernel(
    const float* __restrict__ Xf,
    const float* __restrict__ X0, const float* __restrict__ XL,
    const float* __restrict__ XR,
    const float* __restrict__ W1_, const float* __restrict__ b1_,
    const float* __restrict__ W2_, const float* __restrict__ b2_,
    const float* __restrict__ W3_, const float* __restrict__ b3_,
    const float* __restrict__ W4_, const float* __restrict__ b4_,
    const float* __restrict__ W5_, const float* __restrict__ b5_,
    const float* __restrict__ W6_, const float* __restrict__ b6_,
    const float* __restrict__ W7_, const float* __restrict__ b7_,
    const float* __restrict__ W8_, const float* __restrict__ b8_,
    const float* __restrict__ W9_, const float* __restrict__ b9_,
    float* __restrict__ out_u, float* __restrict__ out_f,
    float* __restrict__ out_ux, float* __restrict__ out_uxx,
    float* __restrict__ O0, float* __restrict__ OL, float* __restrict__ OR_,
    int n_colloc_blocks, int NF2, int N0) {
    // Launder a zero through a VGPR so weight addresses are not provably
    // uniform -> compiler emits global_load (VMEM, VGPR-staged, deep
    // vmcnt-pipelined) instead of s_load (SGPR-window-batched).
    unsigned zv = 0u;
    asm volatile("" : "+v"(zv));
    const float* W1 = W1_ + zv;  const float* b1 = b1_ + zv;
    const float* W2 = W2_ + zv;  const float* b2 = b2_ + zv;
    const float* W3 = W3_ + zv;  const float* b3 = b3_ + zv;
    const float* W4 = W4_ + zv;  const float* b4 = b4_ + zv;
    const float* W5 = W5_ + zv;  const float* b5 = b5_ + zv;
    const float* W6 = W6_ + zv;  const float* b6 = b6_ + zv;
    const float* W7 = W7_ + zv;  const float* b7 = b7_ + zv;
    const float* W8 = W8_ + zv;  const float* b8 = b8_ + zv;
    const float* W9 = W9_ + zv;  const float* b9 = b9_ + zv;

    if ((int)blockIdx.x < n_colloc_blocks) {
        // ------------- collocation path: 2 points, 4 AD channels -------------
        int gid = blockIdx.x * blockDim.x + threadIdx.x;   // pair index
        if (gid >= NF2) return;
        // Points 2*gid and 2*gid+1: one float4 = (x0,t0,x1,t1).
        float4 xt2 = ((const float4*)Xf)[gid];
        float xin[2], tin[2];
        xin[0] = xt2.x; tin[0] = xt2.y;
        xin[1] = xt2.z; tin[1] = xt2.w;

        float h[2][10], hx[2][10], ht[2][10], hxx[2][10];
        // Layer 1: 2 -> 10, tanh. Seeds: dx=(1,0), dt=(0,1), dxx=0.
#pragma unroll
        for (int jp = 0; jp < 5; ++jp) {
            v2f wx2 = *(const v2f*)(W1 + 2 * jp);        // W1 row 0
            v2f wt2 = *(const v2f*)(W1 + 10 + 2 * jp);   // W1 row 1
            v2f b2v = *(const v2f*)(b1 + 2 * jp);
#pragma unroll
            for (int p = 0; p < 2; ++p) {
                v2f z2  = pk_fma(splat2(xin[p]), wx2,
                                 pk_fma(splat2(tin[p]), wt2, b2v));
                v2f v2v = tanh2(z2);
                v2f s2  = pk_fma(-v2v, v2v, splat2(1.0f));
                v2f sx2 = s2 * wx2;
                v2f m2v = splat2(-2.0f) * v2v;
                v2f st2 = s2 * wt2;
                v2f sxx2 = m2v * (sx2 * wx2);   // zxx = 0 at layer 1
                h[p][2*jp]   = v2v.x;  h[p][2*jp+1]   = v2v.y;
                hx[p][2*jp]  = sx2.x;  hx[p][2*jp+1]  = sx2.y;
                ht[p][2*jp]  = st2.x;  ht[p][2*jp+1]  = st2.y;
                hxx[p][2*jp] = sxx2.x; hxx[p][2*jp+1] = sxx2.y;
            }
        }

        hidden10_ad_x2(W2, b2, h, hx, ht, hxx);
        hidden10_ad_x2(W3, b3, h, hx, ht, hxx);
        hidden10_ad_x2(W4, b4, h, hx, ht, hxx);
        hidden10_ad_x2(W5, b5, h, hx, ht, hxx);
        hidden10_ad_x2(W6, b6, h, hx, ht, hxx);
        hidden10_ad_x2(W7, b7, h, hx, ht, hxx);
        hidden10_ad_x2(W8, b8, h, hx, ht, hxx);

        // Layer 9: 10 -> 1, linear. Packed pairwise dot + horizontal add.
        float u[2], ux[2], ut[2], uxx[2];
#pragma unroll
        for (int p = 0; p < 2; ++p) {
            v2f w0 = *(const v2f*)(W9);
            v2f hu, hxu, htu, hxxu;
            hu.x   = h[p][0];   hu.y   = h[p][1];
            hxu.x  = hx[p][0];  hxu.y  = hx[p][1];
            htu.x  = ht[p][0];  htu.y  = ht[p][1];
            hxxu.x = hxx[p][0]; hxxu.y = hxx[p][1];
            v2f su   = hu   * w0;
            v2f sux  = hxu  * w0;
            v2f sut  = htu  * w0;
            v2f suxx = hxxu * w0;
#pragma unroll
            for (int jp = 1; jp < 5; ++jp) {
                v2f w2 = *(const v2f*)(W9 + 2 * jp);
                v2f a, b, c, d;
                a.x = h[p][2*jp];   a.y = h[p][2*jp+1];
                b.x = hx[p][2*jp];  b.y = hx[p][2*jp+1];
                c.x = ht[p][2*jp];  c.y = ht[p][2*jp+1];
                d.x = hxx[p][2*jp]; d.y = hxx[p][2*jp+1];
                su   = pk_fma(a, w2, su);
                sux  = pk_fma(b, w2, sux);
                sut  = pk_fma(c, w2, sut);
                suxx = pk_fma(d, w2, suxx);
            }
            u[p]   = b9[0] + (su.x + su.y);
            ux[p]  = sux.x + sux.y;
            ut[p]  = sut.x + sut.y;
            uxx[p] = suxx.x + suxx.y;
        }

        float2 st;
        st.x = u[0]; st.y = u[1];
        ((float2*)out_u)[gid] = st;
        st.x = ux[0]; st.y = ux[1];
        ((float2*)out_ux)[gid] = st;
        st.x = uxx[0]; st.y = uxx[1];
        ((float2*)out_uxx)[gid] = st;
        st.x = fmaf(u[0], ux[0], ut[0]) - NU_CONST * uxx[0];
        st.y = fmaf(u[1], ux[1], ut[1]) - NU_CONST * uxx[1];
        ((float2*)out_f)[gid] = st;   // u_t + u*u_x - nu*u_xx
    } else {
        // ---------------- forward-only path: IC + boundaries ----------------
        int idx = (blockIdx.x - n_colloc_blocks) * blockDim.x + threadIdx.x;
        if (idx >= 3 * N0) return;
        const float* X;
        float* O;
        int k;
        if (idx < N0)            { X = X0; O = O0;  k = idx; }
        else if (idx < 2 * N0)   { X = XL; O = OL;  k = idx - N0; }
        else                     { X = XR; O = OR_; k = idx - 2 * N0; }

        float2 xt = ((const float2*)X)[k];
        float x = xt.x;
        float t = xt.y;

        float h[10];
#pragma unroll
        for (int j = 0; j < 10; ++j) {
            float z = fmaf(x, W1[j], fmaf(t, W1[10 + j], b1[j]));
            h[j] = fast_tanh(z);
        }
        hidden10_fwd(W2, b2, h);
        hidden10_fwd(W3, b3, h);
        hidden10_fwd(W4, b4, h);
        hidden10_fwd(W5, b5, h);
        hidden10_fwd(W6, b6, h);
        hidden10_fwd(W7, b7, h);
        hidden10_fwd(W8, b8, h);

        float u = b9[0];
#pragma unroll
        for (int i = 0; i < 10; ++i) u = fmaf(h[i], W9[i], u);
        O[k] = u;
    }
}

extern "C" void kernel_launch(void* const* d_in, const int* in_sizes, int n_in,
                              void* d_out, int out_size, void* d_ws, size_t ws_size,
                              hipStream_t stream) {
    const float* Xf = (const float*)d_in[0];
    const float* X0 = (const float*)d_in[1];
    const float* XL = (const float*)d_in[2];
    const float* XR = (const float*)d_in[3];
    const float* W[9];
    const float* B[9];
    for (int i = 0; i < 9; ++i) {
        W[i] = (const float*)d_in[4 + 2 * i];
        B[i] = (const float*)d_in[5 + 2 * i];
    }
    int NF = in_sizes[0] / 2;
    int N0 = in_sizes[1] / 2;
    int NB = in_sizes[2] / 2;
    int NF2 = NF / 2;   // pairs of points (NF = 1048576, even)

    float* out = (float*)d_out;
    float* out_u   = out;                         // u_pred_f      [NF]
    float* out_0   = out + NF;                    // u_pred_0      [N0]
    float* out_bl  = out + NF + N0;               // u_pred_b_left [NB]
    float* out_br  = out + NF + N0 + NB;          // u_pred_b_right[NB]
    float* out_f   = out + NF + N0 + 2 * NB;      // f             [NF]
    float* out_ux  = out_f + NF;                  // u_x           [NF]
    float* out_uxx = out_ux + NF;                 // u_xx          [NF]

    int n_colloc_blocks = (NF2 + 255) / 256;
    int n_fwd_blocks    = (3 * N0 + 255) / 256;
    dim3 blk(256);
    dim3 grd(n_colloc_blocks + n_fwd_blocks);
    pinn_fused_kernel<<<grd, blk, 0, stream>>>(
        Xf, X0, XL, XR,
        W[0], B[0], W[1], B[1], W[2], B[2], W[3], B[3], W[4], B[4],
        W[5], B[5], W[6], B[6], W[7], B[7], W[8], B[8],
        out_u, out_f, out_ux, out_uxx,
        out_0, out_bl, out_br,
        n_colloc_blocks, NF2, N0);
}

// Round 5
// 175.451 us; speedup vs baseline: 1.1148x; 1.0462x over previous
//
#include <hip/hip_runtime.h>
#include <math.h>

// Burgers PINN: u = MLP(x,t) (2->10x7->1, tanh), outputs u, f, u_x, u_xx at 1M
// collocation points + plain forward at 3x16384 IC/boundary points.
// Forward-mode AD with 4 channels: (val, d/dx, d/dt, d2/dx2).
//
// R15: R10 EXACTLY (2 pts/thread, waves_per_eu(2,2), unrolled, kernarg
// s_load weights) + entry PHASE-SKEW via s_sleep. Ledger R10-R14: VALU
// stream constant ~153k cyc/SIMD; idle invariant to weight-fetch path
// (s_load/LDS/VMEM all tried) AND to occupancy 1.7-4.4 w/SIMD; R13 @ 1
// wave/SIMD exposes the raw per-wave stall ~23k cyc. A 2nd wave has 7x the
// compute needed to cover that stall yet hides none of it -> co-resident
// waves run identical code in LOCKSTEP (round-robin issue keeps them
// PC-adjacent; they hit each layer's lgkmcnt wait the same cycle and stall
// together). Fix: desynchronize by ~half a layer period (~1280 cyc) per
// wave slot with s_sleep (no issue slots burned). Slots keyed by
// (blockIdx&1, wave-in-block&1) since co-resident waves on a SIMD come
// from different blocks.

#define NU_CONST 0.0031830988618379067f   // 0.01 / pi
#define TWO_OVER_LN2 2.8853900817779268f  // 2 / ln(2)

typedef float v2f __attribute__((ext_vector_type(2)));

__device__ __forceinline__ v2f splat2(float s) {
    v2f r; r.x = s; r.y = s; return r;
}
__device__ __forceinline__ v2f pk_fma(v2f a, v2f b, v2f c) {
    return __builtin_elementwise_fma(a, b, c);
}

__device__ __forceinline__ float fast_tanh(float x) {
    float e = __builtin_amdgcn_exp2f(x * TWO_OVER_LN2);
    float r = __builtin_amdgcn_rcpf(e + 1.0f);
    return fmaf(-2.0f, r, 1.0f);
}

// Packed tanh on a pair.
__device__ __forceinline__ v2f tanh2(v2f z2) {
    v2f a2 = z2 * splat2(TWO_OVER_LN2);
    v2f e2;
    e2.x = __builtin_amdgcn_exp2f(a2.x);
    e2.y = __builtin_amdgcn_exp2f(a2.y);
    v2f ep = e2 + splat2(1.0f);
    v2f r2;
    r2.x = __builtin_amdgcn_rcpf(ep.x);
    r2.y = __builtin_amdgcn_rcpf(ep.y);
    return pk_fma(splat2(-2.0f), r2, splat2(1.0f));
}

// One hidden 10->10 tanh layer, 4 AD channels, TWO points per thread.
// Each weight pair w2 is loaded once (uniform -> s_load) and feeds 8 pk_fmas.
__device__ __forceinline__ void hidden10_ad_x2(const float* __restrict__ W,
                                               const float* __restrict__ B,
                                               float h[2][10], float hx[2][10],
                                               float ht[2][10], float hxx[2][10]) {
    v2f Z[2][5], Zx[2][5], Zt[2][5], Zxx[2][5];
#pragma unroll
    for (int jp = 0; jp < 5; ++jp) {
        v2f w2 = *(const v2f*)(W + 2 * jp);   // row 0, uniform -> s_load
        v2f b2 = *(const v2f*)(B + 2 * jp);
#pragma unroll
        for (int p = 0; p < 2; ++p) {
            Z[p][jp]   = pk_fma(splat2(h[p][0]), w2, b2);
            Zx[p][jp]  = splat2(hx[p][0]) * w2;
            Zt[p][jp]  = splat2(ht[p][0]) * w2;
            Zxx[p][jp] = splat2(hxx[p][0]) * w2;
        }
    }
#pragma unroll
    for (int i = 1; i < 10; ++i) {
#pragma unroll
        for (int jp = 0; jp < 5; ++jp) {
            v2f w2 = *(const v2f*)(W + i * 10 + 2 * jp);
#pragma unroll
            for (int p = 0; p < 2; ++p) {
                Z[p][jp]   = pk_fma(splat2(h[p][i]),   w2, Z[p][jp]);
                Zx[p][jp]  = pk_fma(splat2(hx[p][i]),  w2, Zx[p][jp]);
                Zt[p][jp]  = pk_fma(splat2(ht[p][i]),  w2, Zt[p][jp]);
                Zxx[p][jp] = pk_fma(splat2(hxx[p][i]), w2, Zxx[p][jp]);
            }
        }
    }
#pragma unroll
    for (int p = 0; p < 2; ++p) {
#pragma unroll
        for (int jp = 0; jp < 5; ++jp) {
            v2f v2v = tanh2(Z[p][jp]);
            v2f s2  = pk_fma(-v2v, v2v, splat2(1.0f));   // 1 - v^2
            v2f sx2 = s2 * Zx[p][jp];
            v2f m2v = splat2(-2.0f) * v2v;
            v2f htn2 = s2 * Zt[p][jp];
            // d2/dx2 tanh(z) = s*zxx + (-2v)*(sx*zx)
            v2f hxxn2 = pk_fma(s2, Zxx[p][jp], m2v * (sx2 * Zx[p][jp]));
            h[p][2*jp]   = v2v.x;   h[p][2*jp+1]   = v2v.y;
            hx[p][2*jp]  = sx2.x;   hx[p][2*jp+1]  = sx2.y;
            ht[p][2*jp]  = htn2.x;  ht[p][2*jp+1]  = htn2.y;
            hxx[p][2*jp] = hxxn2.x; hxx[p][2*jp+1] = hxxn2.y;
        }
    }
}

// Values-only hidden layer (boundary/IC points), packed over j-pairs.
__device__ __forceinline__ void hidden10_fwd(const float* __restrict__ W,
                                             const float* __restrict__ B,
                                             float h[10]) {
    v2f Z[5];
    {
        v2f hs = splat2(h[0]);
#pragma unroll
        for (int jp = 0; jp < 5; ++jp) {
            v2f w2 = *(const v2f*)(W + 2 * jp);
            v2f b2 = *(const v2f*)(B + 2 * jp);
            Z[jp] = pk_fma(hs, w2, b2);
        }
    }
#pragma unroll
    for (int i = 1; i < 10; ++i) {
        v2f hs = splat2(h[i]);
#pragma unroll
        for (int jp = 0; jp < 5; ++jp) {
            v2f w2 = *(const v2f*)(W + i * 10 + 2 * jp);
            Z[jp] = pk_fma(hs, w2, Z[jp]);
        }
    }
#pragma unroll
    for (int jp = 0; jp < 5; ++jp) {
        v2f v2v = tanh2(Z[jp]);
        h[2*jp] = v2v.x;
        h[2*jp+1] = v2v.y;
    }
}

__global__ __launch_bounds__(256)
__attribute__((amdgpu_waves_per_eu(2, 2)))
void pinn_fused_kernel(
    const float* __restrict__ Xf,
    const float* __restrict__ X0, const float* __restrict__ XL,
    const float* __restrict__ XR,
    const float* __restrict__ W1, const float* __restrict__ b1,
    const float* __restrict__ W2, const float* __restrict__ b2,
    const float* __restrict__ W3, const float* __restrict__ b3,
    const float* __restrict__ W4, const float* __restrict__ b4,
    const float* __restrict__ W5, const float* __restrict__ b5,
    const float* __restrict__ W6, const float* __restrict__ b6,
    const float* __restrict__ W7, const float* __restrict__ b7,
    const float* __restrict__ W8, const float* __restrict__ b8,
    const float* __restrict__ W9, const float* __restrict__ b9,
    float* __restrict__ out_u, float* __restrict__ out_f,
    float* __restrict__ out_ux, float* __restrict__ out_uxx,
    float* __restrict__ O0, float* __restrict__ OL, float* __restrict__ OR_,
    int n_colloc_blocks, int NF2, int N0) {
    // ---- Phase-skew: desynchronize co-resident waves' stall windows. ----
    // Co-resident waves on a SIMD come from different 256-thread blocks
    // (each block spreads its 4 waves one-per-SIMD), so key the skew on
    // blockIdx parity first, wave-in-block parity second. Slot spacing
    // ~1280 cyc = about half the per-layer period (~2.5k cyc).
    {
        int wslot = ((blockIdx.x & 1) << 1) | ((threadIdx.x >> 6) & 1);
        switch (wslot) {
            case 1: __builtin_amdgcn_s_sleep(20); break;   // ~1280 cyc
            case 2: __builtin_amdgcn_s_sleep(40); break;   // ~2560 cyc
            case 3: __builtin_amdgcn_s_sleep(60); break;   // ~3840 cyc
            default: break;
        }
    }

    if ((int)blockIdx.x < n_colloc_blocks) {
        // ------------- collocation path: 2 points, 4 AD channels -------------
        int gid = blockIdx.x * blockDim.x + threadIdx.x;   // pair index
        if (gid >= NF2) return;
        // Points 2*gid and 2*gid+1: one float4 = (x0,t0,x1,t1).
        float4 xt2 = ((const float4*)Xf)[gid];
        float xin[2], tin[2];
        xin[0] = xt2.x; tin[0] = xt2.y;
        xin[1] = xt2.z; tin[1] = xt2.w;

        float h[2][10], hx[2][10], ht[2][10], hxx[2][10];
        // Layer 1: 2 -> 10, tanh. Seeds: dx=(1,0), dt=(0,1), dxx=0.
#pragma unroll
        for (int jp = 0; jp < 5; ++jp) {
            v2f wx2 = *(const v2f*)(W1 + 2 * jp);        // W1 row 0
            v2f wt2 = *(const v2f*)(W1 + 10 + 2 * jp);   // W1 row 1
            v2f b2v = *(const v2f*)(b1 + 2 * jp);
#pragma unroll
            for (int p = 0; p < 2; ++p) {
                v2f z2  = pk_fma(splat2(xin[p]), wx2,
                                 pk_fma(splat2(tin[p]), wt2, b2v));
                v2f v2v = tanh2(z2);
                v2f s2  = pk_fma(-v2v, v2v, splat2(1.0f));
                v2f sx2 = s2 * wx2;
                v2f m2v = splat2(-2.0f) * v2v;
                v2f st2 = s2 * wt2;
                v2f sxx2 = m2v * (sx2 * wx2);   // zxx = 0 at layer 1
                h[p][2*jp]   = v2v.x;  h[p][2*jp+1]   = v2v.y;
                hx[p][2*jp]  = sx2.x;  hx[p][2*jp+1]  = sx2.y;
                ht[p][2*jp]  = st2.x;  ht[p][2*jp+1]  = st2.y;
                hxx[p][2*jp] = sxx2.x; hxx[p][2*jp+1] = sxx2.y;
            }
        }

        hidden10_ad_x2(W2, b2, h, hx, ht, hxx);
        hidden10_ad_x2(W3, b3, h, hx, ht, hxx);
        hidden10_ad_x2(W4, b4, h, hx, ht, hxx);
        hidden10_ad_x2(W5, b5, h, hx, ht, hxx);
        hidden10_ad_x2(W6, b6, h, hx, ht, hxx);
        hidden10_ad_x2(W7, b7, h, hx, ht, hxx);
        hidden10_ad_x2(W8, b8, h, hx, ht, hxx);

        // Layer 9: 10 -> 1, linear. Packed pairwise dot + horizontal add.
        float u[2], ux[2], ut[2], uxx[2];
#pragma unroll
        for (int p = 0; p < 2; ++p) {
            v2f w0 = *(const v2f*)(W9);
            v2f hu, hxu, htu, hxxu;
            hu.x   = h[p][0];   hu.y   = h[p][1];
            hxu.x  = hx[p][0];  hxu.y  = hx[p][1];
            htu.x  = ht[p][0];  htu.y  = ht[p][1];
            hxxu.x = hxx[p][0]; hxxu.y = hxx[p][1];
            v2f su   = hu   * w0;
            v2f sux  = hxu  * w0;
            v2f sut  = htu  * w0;
            v2f suxx = hxxu * w0;
#pragma unroll
            for (int jp = 1; jp < 5; ++jp) {
                v2f w2 = *(const v2f*)(W9 + 2 * jp);
                v2f a, b, c, d;
                a.x = h[p][2*jp];   a.y = h[p][2*jp+1];
                b.x = hx[p][2*jp];  b.y = hx[p][2*jp+1];
                c.x = ht[p][2*jp];  c.y = ht[p][2*jp+1];
                d.x = hxx[p][2*jp]; d.y = hxx[p][2*jp+1];
                su   = pk_fma(a, w2, su);
                sux  = pk_fma(b, w2, sux);
                sut  = pk_fma(c, w2, sut);
                suxx = pk_fma(d, w2, suxx);
            }
            u[p]   = b9[0] + (su.x + su.y);
            ux[p]  = sux.x + sux.y;
            ut[p]  = sut.x + sut.y;
            uxx[p] = suxx.x + suxx.y;
        }

        float2 st;
        st.x = u[0]; st.y = u[1];
        ((float2*)out_u)[gid] = st;
        st.x = ux[0]; st.y = ux[1];
        ((float2*)out_ux)[gid] = st;
        st.x = uxx[0]; st.y = uxx[1];
        ((float2*)out_uxx)[gid] = st;
        st.x = fmaf(u[0], ux[0], ut[0]) - NU_CONST * uxx[0];
        st.y = fmaf(u[1], ux[1], ut[1]) - NU_CONST * uxx[1];
        ((float2*)out_f)[gid] = st;   // u_t + u*u_x - nu*u_xx
    } else {
        // ---------------- forward-only path: IC + boundaries ----------------
        int idx = (blockIdx.x - n_colloc_blocks) * blockDim.x + threadIdx.x;
        if (idx >= 3 * N0) return;
        const float* X;
        float* O;
        int k;
        if (idx < N0)            { X = X0; O = O0;  k = idx; }
        else if (idx < 2 * N0)   { X = XL; O = OL;  k = idx - N0; }
        else                     { X = XR; O = OR_; k = idx - 2 * N0; }

        float2 xt = ((const float2*)X)[k];
        float x = xt.x;
        float t = xt.y;

        float h[10];
#pragma unroll
        for (int j = 0; j < 10; ++j) {
            float z = fmaf(x, W1[j], fmaf(t, W1[10 + j], b1[j]));
            h[j] = fast_tanh(z);
        }
        hidden10_fwd(W2, b2, h);
        hidden10_fwd(W3, b3, h);
        hidden10_fwd(W4, b4, h);
        hidden10_fwd(W5, b5, h);
        hidden10_fwd(W6, b6, h);
        hidden10_fwd(W7, b7, h);
        hidden10_fwd(W8, b8, h);

        float u = b9[0];
#pragma unroll
        for (int i = 0; i < 10; ++i) u = fmaf(h[i], W9[i], u);
        O[k] = u;
    }
}

extern "C" void kernel_launch(void* const* d_in, const int* in_sizes, int n_in,
                              void* d_out, int out_size, void* d_ws, size_t ws_size,
                              hipStream_t stream) {
    const float* Xf = (const float*)d_in[0];
    const float* X0 = (const float*)d_in[1];
    const float* XL = (const float*)d_in[2];
    const float* XR = (const float*)d_in[3];
    const float* W[9];
    const float* B[9];
    for (int i = 0; i < 9; ++i) {
        W[i] = (const float*)d_in[4 + 2 * i];
        B[i] = (const float*)d_in[5 + 2 * i];
    }
    int NF = in_sizes[0] / 2;
    int N0 = in_sizes[1] / 2;
    int NB = in_sizes[2] / 2;
    int NF2 = NF / 2;   // pairs of points (NF = 1048576, even)

    float* out = (float*)d_out;
    float* out_u   = out;                         // u_pred_f      [NF]
    float* out_0   = out + NF;                    // u_pred_0      [N0]
    float* out_bl  = out + NF + N0;               // u_pred_b_left [NB]
    float* out_br  = out + NF + N0 + NB;          // u_pred_b_right[NB]
    float* out_f   = out + NF + N0 + 2 * NB;      // f             [NF]
    float* out_ux  = out_f + NF;                  // u_x           [NF]
    float* out_uxx = out_ux + NF;                 // u_xx          [NF]

    int n_colloc_blocks = (NF2 + 255) / 256;
    int n_fwd_blocks    = (3 * N0 + 255) / 256;
    dim3 blk(256);
    dim3 grd(n_colloc_blocks + n_fwd_blocks);
    pinn_fused_kernel<<<grd, blk, 0, stream>>>(
        Xf, X0, XL, XR,
        W[0], B[0], W[1], B[1], W[2], B[2], W[3], B[3], W[4], B[4],
        W[5], B[5], W[6], B[6], W[7], B[7], W[8], B[8],
        out_u, out_f, out_ux, out_uxx,
        out_0, out_bl, out_br,
        n_colloc_blocks, NF2, N0);
}

// Round 6
// 168.941 us; speedup vs baseline: 1.1577x; 1.0385x over previous
//
#include <hip/hip_runtime.h>
#include <math.h>

// Burgers PINN: u = MLP(x,t) (2->10x7->1, tanh), outputs u, f, u_x, u_xx at 1M
// collocation points + plain forward at 3x16384 IC/boundary points.
// Forward-mode AD with 4 channels: (val, d/dx, d/dt, d2/dx2).
//
// R16 = R10 restored (best measured: ~82 us/dispatch, ~168-171 us harness).
// ROOFLINE RATIONALE (R10-R15 ledger): VALU issue stream constant ~153k
// cyc/SIMD across ALL variants (= 4000 v_pk_fma_f32 x 4cyc + ~320 trans +
// misc per wave, 8.75 waves/SIMD). The ~22% non-busy fraction is INVARIANT
// to occupancy (1.7-4.4 w/SIMD; busy rose 59->78% from 1->2 waves then
// FLAT), weight-fetch path (s_load/LDS/VMEM all tried: R11/R14 worse),
// code size (R12 rolled: worse), and wave phase (R15 skew: much worse).
// That is a saturated-execution signature: trans ops (v_exp/v_rcp,
// quarter-rate, ~2.6k cyc/wave) block the wave but aren't counted as
// VALU-busy -> ~78% is the mechanical busy ceiling for this mix.
// Floor arithmetic: 19k cyc/wave x 8.75 /2.2-2.4GHz ~ 70-77 us vs 82
// measured; 7.4 GFLOP / 82us = 90 TF ~ 87% of the 103 TF measured
// v_fma_f32 chip ceiling (m07). MFMA rejected: 10-wide MLP uses <=20% of
// a bf16 fragment and split-precision conversion + cross-lane shuffles
// cost >= the VALU GEMM replaced; no f32-input MFMA on CDNA4.

#define NU_CONST 0.0031830988618379067f   // 0.01 / pi
#define TWO_OVER_LN2 2.8853900817779268f  // 2 / ln(2)

typedef float v2f __attribute__((ext_vector_type(2)));

__device__ __forceinline__ v2f splat2(float s) {
    v2f r; r.x = s; r.y = s; return r;
}
__device__ __forceinline__ v2f pk_fma(v2f a, v2f b, v2f c) {
    return __builtin_elementwise_fma(a, b, c);
}

__device__ __forceinline__ float fast_tanh(float x) {
    float e = __builtin_amdgcn_exp2f(x * TWO_OVER_LN2);
    float r = __builtin_amdgcn_rcpf(e + 1.0f);
    return fmaf(-2.0f, r, 1.0f);
}

// Packed tanh on a pair.
__device__ __forceinline__ v2f tanh2(v2f z2) {
    v2f a2 = z2 * splat2(TWO_OVER_LN2);
    v2f e2;
    e2.x = __builtin_amdgcn_exp2f(a2.x);
    e2.y = __builtin_amdgcn_exp2f(a2.y);
    v2f ep = e2 + splat2(1.0f);
    v2f r2;
    r2.x = __builtin_amdgcn_rcpf(ep.x);
    r2.y = __builtin_amdgcn_rcpf(ep.y);
    return pk_fma(splat2(-2.0f), r2, splat2(1.0f));
}

// One hidden 10->10 tanh layer, 4 AD channels, TWO points per thread.
// Each weight pair w2 is loaded once (uniform -> s_load) and feeds 8 pk_fmas.
__device__ __forceinline__ void hidden10_ad_x2(const float* __restrict__ W,
                                               const float* __restrict__ B,
                                               float h[2][10], float hx[2][10],
                                               float ht[2][10], float hxx[2][10]) {
    v2f Z[2][5], Zx[2][5], Zt[2][5], Zxx[2][5];
#pragma unroll
    for (int jp = 0; jp < 5; ++jp) {
        v2f w2 = *(const v2f*)(W + 2 * jp);   // row 0, uniform -> s_load
        v2f b2 = *(const v2f*)(B + 2 * jp);
#pragma unroll
        for (int p = 0; p < 2; ++p) {
            Z[p][jp]   = pk_fma(splat2(h[p][0]), w2, b2);
            Zx[p][jp]  = splat2(hx[p][0]) * w2;
            Zt[p][jp]  = splat2(ht[p][0]) * w2;
            Zxx[p][jp] = splat2(hxx[p][0]) * w2;
        }
    }
#pragma unroll
    for (int i = 1; i < 10; ++i) {
#pragma unroll
        for (int jp = 0; jp < 5; ++jp) {
            v2f w2 = *(const v2f*)(W + i * 10 + 2 * jp);
#pragma unroll
            for (int p = 0; p < 2; ++p) {
                Z[p][jp]   = pk_fma(splat2(h[p][i]),   w2, Z[p][jp]);
                Zx[p][jp]  = pk_fma(splat2(hx[p][i]),  w2, Zx[p][jp]);
                Zt[p][jp]  = pk_fma(splat2(ht[p][i]),  w2, Zt[p][jp]);
                Zxx[p][jp] = pk_fma(splat2(hxx[p][i]), w2, Zxx[p][jp]);
            }
        }
    }
#pragma unroll
    for (int p = 0; p < 2; ++p) {
#pragma unroll
        for (int jp = 0; jp < 5; ++jp) {
            v2f v2v = tanh2(Z[p][jp]);
            v2f s2  = pk_fma(-v2v, v2v, splat2(1.0f));   // 1 - v^2
            v2f sx2 = s2 * Zx[p][jp];
            v2f m2v = splat2(-2.0f) * v2v;
            v2f htn2 = s2 * Zt[p][jp];
            // d2/dx2 tanh(z) = s*zxx + (-2v)*(sx*zx)
            v2f hxxn2 = pk_fma(s2, Zxx[p][jp], m2v * (sx2 * Zx[p][jp]));
            h[p][2*jp]   = v2v.x;   h[p][2*jp+1]   = v2v.y;
            hx[p][2*jp]  = sx2.x;   hx[p][2*jp+1]  = sx2.y;
            ht[p][2*jp]  = htn2.x;  ht[p][2*jp+1]  = htn2.y;
            hxx[p][2*jp] = hxxn2.x; hxx[p][2*jp+1] = hxxn2.y;
        }
    }
}

// Values-only hidden layer (boundary/IC points), packed over j-pairs.
__device__ __forceinline__ void hidden10_fwd(const float* __restrict__ W,
                                             const float* __restrict__ B,
                                             float h[10]) {
    v2f Z[5];
    {
        v2f hs = splat2(h[0]);
#pragma unroll
        for (int jp = 0; jp < 5; ++jp) {
            v2f w2 = *(const v2f*)(W + 2 * jp);
            v2f b2 = *(const v2f*)(B + 2 * jp);
            Z[jp] = pk_fma(hs, w2, b2);
        }
    }
#pragma unroll
    for (int i = 1; i < 10; ++i) {
        v2f hs = splat2(h[i]);
#pragma unroll
        for (int jp = 0; jp < 5; ++jp) {
            v2f w2 = *(const v2f*)(W + i * 10 + 2 * jp);
            Z[jp] = pk_fma(hs, w2, Z[jp]);
        }
    }
#pragma unroll
    for (int jp = 0; jp < 5; ++jp) {
        v2f v2v = tanh2(Z[jp]);
        h[2*jp] = v2v.x;
        h[2*jp+1] = v2v.y;
    }
}

__global__ __launch_bounds__(256)
__attribute__((amdgpu_waves_per_eu(2, 2)))
void pinn_fused_kernel(
    const float* __restrict__ Xf,
    const float* __restrict__ X0, const float* __restrict__ XL,
    const float* __restrict__ XR,
    const float* __restrict__ W1, const float* __restrict__ b1,
    const float* __restrict__ W2, const float* __restrict__ b2,
    const float* __restrict__ W3, const float* __restrict__ b3,
    const float* __restrict__ W4, const float* __restrict__ b4,
    const float* __restrict__ W5, const float* __restrict__ b5,
    const float* __restrict__ W6, const float* __restrict__ b6,
    const float* __restrict__ W7, const float* __restrict__ b7,
    const float* __restrict__ W8, const float* __restrict__ b8,
    const float* __restrict__ W9, const float* __restrict__ b9,
    float* __restrict__ out_u, float* __restrict__ out_f,
    float* __restrict__ out_ux, float* __restrict__ out_uxx,
    float* __restrict__ O0, float* __restrict__ OL, float* __restrict__ OR_,
    int n_colloc_blocks, int NF2, int N0) {
    if ((int)blockIdx.x < n_colloc_blocks) {
        // ------------- collocation path: 2 points, 4 AD channels -------------
        int gid = blockIdx.x * blockDim.x + threadIdx.x;   // pair index
        if (gid >= NF2) return;
        // Points 2*gid and 2*gid+1: one float4 = (x0,t0,x1,t1).
        float4 xt2 = ((const float4*)Xf)[gid];
        float xin[2], tin[2];
        xin[0] = xt2.x; tin[0] = xt2.y;
        xin[1] = xt2.z; tin[1] = xt2.w;

        float h[2][10], hx[2][10], ht[2][10], hxx[2][10];
        // Layer 1: 2 -> 10, tanh. Seeds: dx=(1,0), dt=(0,1), dxx=0.
#pragma unroll
        for (int jp = 0; jp < 5; ++jp) {
            v2f wx2 = *(const v2f*)(W1 + 2 * jp);        // W1 row 0
            v2f wt2 = *(const v2f*)(W1 + 10 + 2 * jp);   // W1 row 1
            v2f b2v = *(const v2f*)(b1 + 2 * jp);
#pragma unroll
            for (int p = 0; p < 2; ++p) {
                v2f z2  = pk_fma(splat2(xin[p]), wx2,
                                 pk_fma(splat2(tin[p]), wt2, b2v));
                v2f v2v = tanh2(z2);
                v2f s2  = pk_fma(-v2v, v2v, splat2(1.0f));
                v2f sx2 = s2 * wx2;
                v2f m2v = splat2(-2.0f) * v2v;
                v2f st2 = s2 * wt2;
                v2f sxx2 = m2v * (sx2 * wx2);   // zxx = 0 at layer 1
                h[p][2*jp]   = v2v.x;  h[p][2*jp+1]   = v2v.y;
                hx[p][2*jp]  = sx2.x;  hx[p][2*jp+1]  = sx2.y;
                ht[p][2*jp]  = st2.x;  ht[p][2*jp+1]  = st2.y;
                hxx[p][2*jp] = sxx2.x; hxx[p][2*jp+1] = sxx2.y;
            }
        }

        hidden10_ad_x2(W2, b2, h, hx, ht, hxx);
        hidden10_ad_x2(W3, b3, h, hx, ht, hxx);
        hidden10_ad_x2(W4, b4, h, hx, ht, hxx);
        hidden10_ad_x2(W5, b5, h, hx, ht, hxx);
        hidden10_ad_x2(W6, b6, h, hx, ht, hxx);
        hidden10_ad_x2(W7, b7, h, hx, ht, hxx);
        hidden10_ad_x2(W8, b8, h, hx, ht, hxx);

        // Layer 9: 10 -> 1, linear. Packed pairwise dot + horizontal add.
        float u[2], ux[2], ut[2], uxx[2];
#pragma unroll
        for (int p = 0; p < 2; ++p) {
            v2f w0 = *(const v2f*)(W9);
            v2f hu, hxu, htu, hxxu;
            hu.x   = h[p][0];   hu.y   = h[p][1];
            hxu.x  = hx[p][0];  hxu.y  = hx[p][1];
            htu.x  = ht[p][0];  htu.y  = ht[p][1];
            hxxu.x = hxx[p][0]; hxxu.y = hxx[p][1];
            v2f su   = hu   * w0;
            v2f sux  = hxu  * w0;
            v2f sut  = htu  * w0;
            v2f suxx = hxxu * w0;
#pragma unroll
            for (int jp = 1; jp < 5; ++jp) {
                v2f w2 = *(const v2f*)(W9 + 2 * jp);
                v2f a, b, c, d;
                a.x = h[p][2*jp];   a.y = h[p][2*jp+1];
                b.x = hx[p][2*jp];  b.y = hx[p][2*jp+1];
                c.x = ht[p][2*jp];  c.y = ht[p][2*jp+1];
                d.x = hxx[p][2*jp]; d.y = hxx[p][2*jp+1];
                su   = pk_fma(a, w2, su);
                sux  = pk_fma(b, w2, sux);
                sut  = pk_fma(c, w2, sut);
                suxx = pk_fma(d, w2, suxx);
            }
            u[p]   = b9[0] + (su.x + su.y);
            ux[p]  = sux.x + sux.y;
            ut[p]  = sut.x + sut.y;
            uxx[p] = suxx.x + suxx.y;
        }

        float2 st;
        st.x = u[0]; st.y = u[1];
        ((float2*)out_u)[gid] = st;
        st.x = ux[0]; st.y = ux[1];
        ((float2*)out_ux)[gid] = st;
        st.x = uxx[0]; st.y = uxx[1];
        ((float2*)out_uxx)[gid] = st;
        st.x = fmaf(u[0], ux[0], ut[0]) - NU_CONST * uxx[0];
        st.y = fmaf(u[1], ux[1], ut[1]) - NU_CONST * uxx[1];
        ((float2*)out_f)[gid] = st;   // u_t + u*u_x - nu*u_xx
    } else {
        // ---------------- forward-only path: IC + boundaries ----------------
        int idx = (blockIdx.x - n_colloc_blocks) * blockDim.x + threadIdx.x;
        if (idx >= 3 * N0) return;
        const float* X;
        float* O;
        int k;
        if (idx < N0)            { X = X0; O = O0;  k = idx; }
        else if (idx < 2 * N0)   { X = XL; O = OL;  k = idx - N0; }
        else                     { X = XR; O = OR_; k = idx - 2 * N0; }

        float2 xt = ((const float2*)X)[k];
        float x = xt.x;
        float t = xt.y;

        float h[10];
#pragma unroll
        for (int j = 0; j < 10; ++j) {
            float z = fmaf(x, W1[j], fmaf(t, W1[10 + j], b1[j]));
            h[j] = fast_tanh(z);
        }
        hidden10_fwd(W2, b2, h);
        hidden10_fwd(W3, b3, h);
        hidden10_fwd(W4, b4, h);
        hidden10_fwd(W5, b5, h);
        hidden10_fwd(W6, b6, h);
        hidden10_fwd(W7, b7, h);
        hidden10_fwd(W8, b8, h);

        float u = b9[0];
#pragma unroll
        for (int i = 0; i < 10; ++i) u = fmaf(h[i], W9[i], u);
        O[k] = u;
    }
}

extern "C" void kernel_launch(void* const* d_in, const int* in_sizes, int n_in,
                              void* d_out, int out_size, void* d_ws, size_t ws_size,
                              hipStream_t stream) {
    const float* Xf = (const float*)d_in[0];
    const float* X0 = (const float*)d_in[1];
    const float* XL = (const float*)d_in[2];
    const float* XR = (const float*)d_in[3];
    const float* W[9];
    const float* B[9];
    for (int i = 0; i < 9; ++i) {
        W[i] = (const float*)d_in[4 + 2 * i];
        B[i] = (const float*)d_in[5 + 2 * i];
    }
    int NF = in_sizes[0] / 2;
    int N0 = in_sizes[1] / 2;
    int NB = in_sizes[2] / 2;
    int NF2 = NF / 2;   // pairs of points (NF = 1048576, even)

    float* out = (float*)d_out;
    float* out_u   = out;                         // u_pred_f      [NF]
    float* out_0   = out + NF;                    // u_pred_0      [N0]
    float* out_bl  = out + NF + N0;               // u_pred_b_left [NB]
    float* out_br  = out + NF + N0 + NB;          // u_pred_b_right[NB]
    float* out_f   = out + NF + N0 + 2 * NB;      // f             [NF]
    float* out_ux  = out_f + NF;                  // u_x           [NF]
    float* out_uxx = out_ux + NF;                 // u_xx          [NF]

    int n_colloc_blocks = (NF2 + 255) / 256;
    int n_fwd_blocks    = (3 * N0 + 255) / 256;
    dim3 blk(256);
    dim3 grd(n_colloc_blocks + n_fwd_blocks);
    pinn_fused_kernel<<<grd, blk, 0, stream>>>(
        Xf, X0, XL, XR,
        W[0], B[0], W[1], B[1], W[2], B[2], W[3], B[3], W[4], B[4],
        W[5], B[5], W[6], B[6], W[7], B[7], W[8], B[8],
        out_u, out_f, out_ux, out_uxx,
        out_0, out_bl, out_br,
        n_colloc_blocks, NF2, N0);
}